// Round 15
// baseline (333.075 us; speedup 1.0000x reference)
//
#include <hip/hip_runtime.h>
#include <hip/hip_bf16.h>

// EncoderLayer on MI355X (gfx950).
// B=2, S=2048, D=1024, H=16, DK=64. M = B*S = 4096.
// R15: attention + T15 att[2] double-pipeline (m214v36 +7-11%): QK^T(t+1)
//      issues on the MFMA pipe before softmax(t)+PV(t) runs on VALU; two
//      named S-states (sacc0/sacc1, parity-unrolled, rule #20); V ring-3
//      (16 iters, (t+2)=(t-1) mod 3 -> race-free w/ one barrier/iter);
//      launch_bounds(512,2) -> <=256 VGPR at the LDS-bound 2 waves/SIMD.
//      Everything else identical to R14.

using bf16 = __hip_bfloat16;
typedef __attribute__((ext_vector_type(4))) float f32x4;
typedef __attribute__((ext_vector_type(16))) float f32x16;
typedef __attribute__((ext_vector_type(8))) short bf16x8;

#define DEVI static __device__ __forceinline__

DEVI void async_copy16(const void* g, void* l) {
  __builtin_amdgcn_global_load_lds(
      (const __attribute__((address_space(1))) void*)g,
      (__attribute__((address_space(3))) void*)l, 16, 0, 0);
}

DEVI ushort f2bf_bits(float v) {
  __hip_bfloat16 h = __float2bfloat16(v);
  return *reinterpret_cast<ushort*>(&h);
}

DEVI float bfbits2f(ushort u) {
  union { float f; unsigned int i; } x;
  x.i = ((unsigned int)u) << 16;
  return x.f;
}

DEVI unsigned int pk2(float lo, float hi) {
  return (unsigned int)f2bf_bits(lo) | ((unsigned int)f2bf_bits(hi) << 16);
}

// ---- merged: weight transposes (blocks 0..12287) + LN1 (blocks 12288+) ----
__global__ __launch_bounds__(256) void transpose_all_ln(
    const float* __restrict__ q, const float* __restrict__ k,
    const float* __restrict__ v, const float* __restrict__ o,
    const float* __restrict__ w1, const float* __restrict__ w2,
    bf16* __restrict__ wqkvo, bf16* __restrict__ w1t, bf16* __restrict__ w2t,
    const float* __restrict__ X, const float* __restrict__ g1,
    const float* __restrict__ b1, bf16* __restrict__ xn) {
  const int tid = blockIdx.x;
  if (tid >= 12288) {
    const long row = tid - 12288;
    const int t = threadIdx.x;
    float4 x = ((const float4*)(X + row * 1024))[t];
    float s = x.x + x.y + x.z + x.w;
    float s2 = x.x * x.x + x.y * x.y + x.z * x.z + x.w * x.w;
#pragma unroll
    for (int m = 1; m < 64; m <<= 1) {
      s += __shfl_xor(s, m);
      s2 += __shfl_xor(s2, m);
    }
    __shared__ float red[8];
    const int w = t >> 6, l = t & 63;
    if (l == 0) { red[w] = s; red[4 + w] = s2; }
    __syncthreads();
    s = red[0] + red[1] + red[2] + red[3];
    s2 = red[4] + red[5] + red[6] + red[7];
    const float mean = s * (1.0f / 1024.0f);
    const float var = s2 * (1.0f / 1024.0f) - mean * mean;
    const float rstd = rsqrtf(var + 1e-6f);
    float4 g4 = ((const float4*)g1)[t];
    float4 b4 = ((const float4*)b1)[t];
    union { ushort h[4]; uint2 u; } oo;
    oo.h[0] = f2bf_bits(g4.x * (x.x - mean) * rstd + b4.x);
    oo.h[1] = f2bf_bits(g4.y * (x.y - mean) * rstd + b4.y);
    oo.h[2] = f2bf_bits(g4.z * (x.z - mean) * rstd + b4.z);
    oo.h[3] = f2bf_bits(g4.w * (x.w - mean) * rstd + b4.w);
    ((uint2*)(xn + row * 1024))[t] = oo.u;
    return;
  }
  const float* W;
  bf16* Wt;
  int K, N, n0, k0;
  if (tid < 4096) {
    const int z = tid >> 10, r = tid & 1023;
    W = (z == 0) ? q : (z == 1) ? k : (z == 2) ? v : o;
    Wt = wqkvo + (size_t)z * 1024 * 1024;
    K = 1024; N = 1024; n0 = (r & 31) << 5; k0 = (r >> 5) << 5;
  } else if (tid < 8192) {
    const int r = tid - 4096;
    W = w1; Wt = w1t; K = 1024; N = 4096;
    n0 = (r & 127) << 5; k0 = (r >> 7) << 5;
  } else {
    const int r = tid - 8192;
    W = w2; Wt = w2t; K = 4096; N = 1024;
    n0 = (r & 31) << 5; k0 = (r >> 5) << 5;
  }
  __shared__ float tile[32][33];
  const int tx = threadIdx.x & 31, ty = threadIdx.x >> 5;
#pragma unroll
  for (int i = 0; i < 32; i += 8)
    tile[ty + i][tx] = W[(long)(k0 + ty + i) * N + n0 + tx];
  __syncthreads();
#pragma unroll
  for (int i = 0; i < 32; i += 8)
    Wt[(long)(n0 + ty + i) * K + k0 + tx] = __float2bfloat16(tile[tx][ty + i]);
}

// ---- O-proj split-K reduce fused with LN2: res = p0+p1+X; xn = LN(res) ----
__global__ __launch_bounds__(256) void oproj_reduce_ln(
    const float* __restrict__ p0, const float* __restrict__ p1,
    const float* __restrict__ X, const float* __restrict__ gamma,
    const float* __restrict__ beta, float* __restrict__ res_out,
    bf16* __restrict__ xn_out) {
  const long row = blockIdx.x;
  const int t = threadIdx.x;
  const long i = row * 256 + t;
  const float4 a = ((const float4*)p0)[i];
  const float4 b = ((const float4*)p1)[i];
  const float4 c = ((const float4*)X)[i];
  float4 x;
  x.x = a.x + b.x + c.x; x.y = a.y + b.y + c.y;
  x.z = a.z + b.z + c.z; x.w = a.w + b.w + c.w;
  ((float4*)res_out)[i] = x;
  float s = x.x + x.y + x.z + x.w;
  float s2 = x.x * x.x + x.y * x.y + x.z * x.z + x.w * x.w;
#pragma unroll
  for (int m = 1; m < 64; m <<= 1) {
    s += __shfl_xor(s, m);
    s2 += __shfl_xor(s2, m);
  }
  __shared__ float red[8];
  const int w = t >> 6, l = t & 63;
  if (l == 0) { red[w] = s; red[4 + w] = s2; }
  __syncthreads();
  s = red[0] + red[1] + red[2] + red[3];
  s2 = red[4] + red[5] + red[6] + red[7];
  const float mean = s * (1.0f / 1024.0f);
  const float var = s2 * (1.0f / 1024.0f) - mean * mean;
  const float rstd = rsqrtf(var + 1e-6f);
  float4 g4 = ((const float4*)gamma)[t];
  float4 b4 = ((const float4*)beta)[t];
  union { ushort h[4]; uint2 u; } o;
  o.h[0] = f2bf_bits(g4.x * (x.x - mean) * rstd + b4.x);
  o.h[1] = f2bf_bits(g4.y * (x.y - mean) * rstd + b4.y);
  o.h[2] = f2bf_bits(g4.z * (x.z - mean) * rstd + b4.z);
  o.h[3] = f2bf_bits(g4.w * (x.w - mean) * rstd + b4.w);
  ((uint2*)(xn_out + row * 1024))[t] = o.u;
}

// ---------------- GEMM: C(MxN) = A(MxK,bf16) * Bt(NxK,bf16)^T ----------------
// 128x128 tile, BK=64, 4 waves. A ring-3 (depth-2 prefetch) + B dbuf, counted
// vmcnt(12)/(8)/(0); barrier pair per iter. 80KB LDS (2 blocks/CU).
template <int EPI, int KSPLIT>
__global__ __launch_bounds__(256) void gemm_bt(
    const bf16* __restrict__ A, const bf16* __restrict__ Bt,
    const int M, const int N, const int K, const int lda, const int ldb,
    const float* __restrict__ bias, const float* __restrict__ res,
    float* __restrict__ pother, void* __restrict__ Cout) {
  __shared__ __align__(16) char gsmem[81920];
  const int t = threadIdx.x;
  const int w = t >> 6, l = t & 63;
  const int nb = N >> 7;
  const int cpx = gridDim.x >> 3;
  int bidx = (blockIdx.x & 7) * cpx + (blockIdx.x >> 3);
  int sl = 0;
  if (KSPLIT == 2) {
    const int half = gridDim.x >> 1;
    sl = bidx >= half;
    bidx -= sl * half;
  }
  const int bm = bidx / nb, bn = bidx % nb;
  const long row0 = (long)bm << 7, col0 = (long)bn << 7;
  const int wr = (w >> 1) << 6, wc = (w & 1) << 6;
  const int lr = l & 15;
  const int lkb = (l >> 4) << 4;

  f32x4 acc[4][4];
#pragma unroll
  for (int m = 0; m < 4; ++m)
#pragma unroll
    for (int n = 0; n < 4; ++n) acc[m][n] = (f32x4){0.f, 0.f, 0.f, 0.f};

  const int rA = t >> 3;
  const int g = (t & 7) ^ ((t >> 3) & 7);
  const bf16* gA = A + (row0 + rA) * (long)lda + (long)sl * K + g * 8;
  const bf16* gB = Bt + (col0 + rA) * (long)ldb + (long)sl * K + g * 8;
  char* const Bbase = gsmem + 49152;

  const int nt = K >> 6;
#pragma unroll
  for (int cr = 0; cr < 4; ++cr)
    async_copy16(gA + (long)cr * 32 * lda, gsmem + t * 16 + cr * 4096);
#pragma unroll
  for (int cr = 0; cr < 4; ++cr)
    async_copy16(gB + (long)cr * 32 * ldb, Bbase + t * 16 + cr * 4096);
#pragma unroll
  for (int cr = 0; cr < 4; ++cr)
    async_copy16(gA + (long)cr * 32 * lda + 64, gsmem + 16384 + t * 16 + cr * 4096);
  int curB = 0;

  for (int kt = 0; kt < nt; ++kt) {
    if (kt + 1 < nt) {
      const int k1 = (kt + 1) << 6;
      char* dstB = Bbase + (curB ^ 1) * 16384;
#pragma unroll
      for (int cr = 0; cr < 4; ++cr)
        async_copy16(gB + (long)cr * 32 * ldb + k1, dstB + t * 16 + cr * 4096);
    }
    if (kt + 2 < nt) {
      const int k2 = (kt + 2) << 6;
      char* dstA = gsmem + ((kt + 2) % 3) * 16384;
#pragma unroll
      for (int cr = 0; cr < 4; ++cr)
        async_copy16(gA + (long)cr * 32 * lda + k2, dstA + t * 16 + cr * 4096);
    }
    if (kt < nt - 2) {
      asm volatile("s_waitcnt vmcnt(12)" ::: "memory");
    } else if (kt == nt - 2) {
      asm volatile("s_waitcnt vmcnt(8)" ::: "memory");
    } else {
      asm volatile("s_waitcnt vmcnt(0)" ::: "memory");
    }
    __builtin_amdgcn_s_barrier();
    __builtin_amdgcn_sched_barrier(0);
    const char* As = gsmem + (kt % 3) * 16384;
    const char* Bs = Bbase + curB * 16384;
#pragma unroll
    for (int ks = 0; ks < 2; ++ks) {
      bf16x8 af[4], bfr[4];
#pragma unroll
      for (int m = 0; m < 4; ++m) {
        const int row = wr + m * 16 + lr;
        af[m] = *(const bf16x8*)(As +
            (row * 128 + ((ks * 64 + lkb) ^ ((row & 7) << 4))));
      }
#pragma unroll
      for (int n = 0; n < 4; ++n) {
        const int row = wc + n * 16 + lr;
        bfr[n] = *(const bf16x8*)(Bs +
            (row * 128 + ((ks * 64 + lkb) ^ ((row & 7) << 4))));
      }
#pragma unroll
      for (int m = 0; m < 4; ++m)
#pragma unroll
        for (int n = 0; n < 4; ++n)
          acc[m][n] = __builtin_amdgcn_mfma_f32_16x16x32_bf16(af[m], bfr[n], acc[m][n], 0, 0, 0);
    }
    __builtin_amdgcn_sched_barrier(0);
    __builtin_amdgcn_s_barrier();
    curB ^= 1;
  }

  bf16* Cb = (bf16*)Cout;
  float* Cf = (float*)Cout;
  if ((EPI == 4 || EPI == 5) && sl == 1) Cf = pother;
#pragma unroll
  for (int m = 0; m < 4; ++m) {
#pragma unroll
    for (int r = 0; r < 4; ++r) {
      const long crow = row0 + wr + m * 16 + ((l >> 4) << 2) + r;
      const long rbase = crow * N;
#pragma unroll
      for (int n = 0; n < 4; ++n) {
        const long ccol = col0 + wc + n * 16 + lr;
        float v = acc[m][n][r];
        if (EPI == 2) {
          const float vv = v + bias[ccol];
          const float u2 = vv * (1.5957691216f + 0.0713548162f * vv * vv);
          v = vv / (1.0f + __expf(-u2));
        }
        if (EPI == 5 && sl == 0) v += bias[ccol] + res[rbase + ccol];
        if (EPI == 0 || EPI == 2)
          Cb[rbase + ccol] = __float2bfloat16(v);
        else
          Cf[rbase + ccol] = v;
      }
    }
  }
}

// ---- split-K reduce: out = p0 + p1 (p0 already holds bias+residual) ----
__global__ __launch_bounds__(256) void ff2_reduce(
    const float* __restrict__ p0, const float* __restrict__ p1,
    float* __restrict__ out) {
  const int idx = blockIdx.x * 256 + threadIdx.x;
  const float4 x = ((const float4*)p0)[idx];
  const float4 y = ((const float4*)p1)[idx];
  float4 a;
  a.x = x.x + y.x; a.y = x.y + y.y; a.z = x.z + y.z; a.w = x.w + y.w;
  ((float4*)out)[idx] = a;
}

// ---------------- flash attention: 8 waves, 256 q-rows, KVBLK=128 ------------
// T5 setprio; T13 defer-rescale; permlane32_swap pack; R15: T15 att[2]
// pipeline (QK^T(t+1) before softmax(t)+PV(t)); K dbuf 2x16K, V ring 3x16K.
__global__ __launch_bounds__(512, 2) void attn_kernel(
    const bf16* __restrict__ QKV, const int* __restrict__ pmask,
    bf16* __restrict__ Oout) {
  const int bh = blockIdx.x;
  const int b = bh >> 4, h = bh & 15;
  const int q0 = blockIdx.y << 8;
  const int t = threadIdx.x;
  const int w = t >> 6, l = t & 63;
  const int lq = l & 31, hi = l >> 5;

  __shared__ __align__(16) char smem[81920];  // KB 2x16K @0; VB 3x16K @32768

  const long base = (long)b * 2048 * 3072;
  const bf16* Qg = QKV + base + h * 64;
  const bf16* Kg = QKV + base + 1024 + h * 64;
  const bf16* Vg = QKV + base + 2048 + h * 64;

  int kSrc[2], kDst[2], vk[2], vsg[2];
#pragma unroll
  for (int p = 0; p < 2; ++p) {
    const int c = p * 512 + t;
    const int kr = c >> 3;
    kSrc[p] = kr * 3072 + (((c & 7) ^ (kr & 7)) << 3);
    kDst[p] = c * 16;
    vk[p] = c >> 3;
    vsg[p] = c & 7;
  }

  const int qw0 = q0 + w * 32;
  bf16x8 qf[4];
#pragma unroll
  for (int dc = 0; dc < 4; ++dc) {
    uint4 raw = *(const uint4*)(Qg + (long)(qw0 + lq) * 3072 + dc * 16 + hi * 8);
    union { uint4 u4; ushort us[8]; } in; in.u4 = raw;
    union { bf16x8 v; ushort us[8]; } o;
#pragma unroll
    for (int e = 0; e < 8; ++e) o.us[e] = f2bf_bits(0.125f * bfbits2f(in.us[e]));
    qf[dc] = o.v;
  }

  union { unsigned int u[4]; bf16x8 v; } bones;
  bones.u[0] = (hi == 0) ? 0x00003F80u : 0u;
  bones.u[1] = bones.u[2] = bones.u[3] = 0u;

  uint4 vreg[2];
  // ---- prologue: stage tiles 0 and 1 ----
#pragma unroll
  for (int p = 0; p < 2; ++p) {
    vreg[p] = *(const uint4*)(Vg + (long)vk[p] * 3072 + vsg[p] * 8);
    async_copy16(Kg + kSrc[p], smem + kDst[p]);
  }
#pragma unroll
  for (int p = 0; p < 2; ++p) {
    const ushort* vs = (const ushort*)&vreg[p];
#pragma unroll
    for (int e = 0; e < 8; ++e) {
      const int d = vsg[p] * 8 + e;
      *(ushort*)(smem + 32768 + d * 256 +
                 ((vk[p] * 2) ^ (((e ^ vsg[p]) & 7) << 4))) = vs[e];
    }
  }
#pragma unroll
  for (int p = 0; p < 2; ++p) {
    vreg[p] = *(const uint4*)(Vg + (long)(128 + vk[p]) * 3072 + vsg[p] * 8);
    async_copy16(Kg + (long)128 * 3072 + kSrc[p], smem + 16384 + kDst[p]);
  }
#pragma unroll
  for (int p = 0; p < 2; ++p) {
    const ushort* vs = (const ushort*)&vreg[p];
#pragma unroll
    for (int e = 0; e < 8; ++e) {
      const int d = vsg[p] * 8 + e;
      *(ushort*)(smem + 32768 + 16384 + d * 256 +
                 ((vk[p] * 2) ^ (((e ^ vsg[p]) & 7) << 4))) = vs[e];
    }
  }

  f32x16 oacc[2];
#pragma unroll
  for (int nt = 0; nt < 2; ++nt)
#pragma unroll
    for (int r = 0; r < 16; ++r) oacc[nt][r] = 0.f;
  float mrun = -3.0e38f, lsum = 0.f;

  // QK^T(tile) -> s (reads KB[tile&1]); includes mask rank-1 addend
  auto qkt = [&](f32x16 (&s)[4], int tile) {
    const char* Ks = smem + (tile & 1) * 16384;
    __builtin_amdgcn_s_setprio(1);
#pragma unroll
    for (int kt = 0; kt < 4; ++kt) {
#pragma unroll
      for (int r = 0; r < 16; ++r) s[kt][r] = 0.f;
#pragma unroll
      for (int dc = 0; dc < 4; ++dc) {
        bf16x8 ka = *(const bf16x8*)(Ks +
            ((kt * 32 + lq) * 128 + ((dc * 32 + hi * 16) ^ ((lq & 7) << 4))));
        s[kt] = __builtin_amdgcn_mfma_f32_32x32x16_bf16(ka, qf[dc], s[kt], 0, 0, 0);
      }
      const int mv = pmask[b * 2048 + tile * 128 + kt * 32 + lq];
      union { unsigned int u[4]; bf16x8 v; } aadd;
      aadd.u[0] = (hi == 0 && mv == 0) ? (unsigned int)f2bf_bits(-1.0e9f) : 0u;
      aadd.u[1] = aadd.u[2] = aadd.u[3] = 0u;
      s[kt] = __builtin_amdgcn_mfma_f32_32x32x16_bf16(aadd.v, bones.v, s[kt], 0, 0, 0);
    }
    __builtin_amdgcn_s_setprio(0);
  };

  // one pipeline step: cur = S(tile) ready; computes softmax+PV(tile),
  // prefetches tile+2, and fills nxt = S(tile+1).
  auto iter = [&](f32x16 (&cur)[4], f32x16 (&nxt)[4], int tile) {
    __syncthreads();  // publish staging for tile+1 (K landed, V scattered)
    if (tile + 2 < 16) {
      const long nrow0 = (long)(tile + 2) * 128 * 3072;
#pragma unroll
      for (int p = 0; p < 2; ++p) {
        vreg[p] = *(const uint4*)(Vg + nrow0 + (long)vk[p] * 3072 + vsg[p] * 8);
        async_copy16(Kg + nrow0 + kSrc[p], smem + (tile & 1) * 16384 + kDst[p]);
      }
    }
    if (tile < 15) qkt(nxt, tile + 1);  // MFMA pipe fills nxt under softmax VALU

    // ---- softmax(tile) on cur; defer-rescale THR=8 ----
    float tmax = -3.0e38f;
#pragma unroll
    for (int kt = 0; kt < 4; ++kt)
#pragma unroll
      for (int r = 0; r < 16; ++r) tmax = fmaxf(tmax, cur[kt][r]);
    tmax = fmaxf(tmax, __shfl_xor(tmax, 32));
    const bool need = (bool)__any(tmax > mrun + 8.0f);
    const float mnew = need ? fmaxf(mrun, tmax) : mrun;
    float psum = 0.f;
#pragma unroll
    for (int kt = 0; kt < 4; ++kt)
#pragma unroll
      for (int r = 0; r < 16; ++r) {
        const float p = __expf(cur[kt][r] - mnew);
        cur[kt][r] = p;
        psum += p;
      }
    psum += __shfl_xor(psum, 32);
    if (need) {
      const float alpha = __expf(mrun - mnew);
      mrun = mnew;
      lsum = lsum * alpha + psum;
#pragma unroll
      for (int r = 0; r < 16; ++r) {
        const float ar = __shfl(alpha, (r & 3) + 8 * (r >> 2) + 4 * hi);
        oacc[0][r] *= ar;
        oacc[1][r] *= ar;
      }
    } else {
      lsum += psum;
    }

    // ---- P -> A-fragments via pack + permlane32_swap ----
    union { unsigned int u[4]; bf16x8 v; } paE[4], paO[4];
#pragma unroll
    for (int kt = 0; kt < 4; ++kt) {
      unsigned int c0 = pk2(cur[kt][0], cur[kt][1]);
      unsigned int c1 = pk2(cur[kt][2], cur[kt][3]);
      unsigned int c2 = pk2(cur[kt][4], cur[kt][5]);
      unsigned int c3 = pk2(cur[kt][6], cur[kt][7]);
      unsigned int c4 = pk2(cur[kt][8], cur[kt][9]);
      unsigned int c5 = pk2(cur[kt][10], cur[kt][11]);
      unsigned int c6 = pk2(cur[kt][12], cur[kt][13]);
      unsigned int c7 = pk2(cur[kt][14], cur[kt][15]);
      asm volatile("v_permlane32_swap_b32 %0, %1" : "+v"(c0), "+v"(c2));
      asm volatile("v_permlane32_swap_b32 %0, %1" : "+v"(c1), "+v"(c3));
      asm volatile("v_permlane32_swap_b32 %0, %1" : "+v"(c4), "+v"(c6));
      asm volatile("v_permlane32_swap_b32 %0, %1" : "+v"(c5), "+v"(c7));
      paE[kt].u[0] = c0; paE[kt].u[1] = c1; paE[kt].u[2] = c2; paE[kt].u[3] = c3;
      paO[kt].u[0] = c4; paO[kt].u[1] = c5; paO[kt].u[2] = c6; paO[kt].u[3] = c7;
    }

    // ---- O += P V (reads VB[tile%3]) ----
    const char* Vt = smem + 32768 + (tile % 3) * 16384;
    __builtin_amdgcn_s_setprio(1);
#pragma unroll
    for (int kt = 0; kt < 4; ++kt)
#pragma unroll
      for (int nt = 0; nt < 2; ++nt) {
        const int vrow = nt * 32 + lq;
        const int vsw = ((vrow & 7) ^ ((vrow >> 3) & 7)) << 4;
        bf16x8 vbE = *(const bf16x8*)(Vt + (vrow * 256 + ((kt * 64 + hi * 16) ^ vsw)));
        oacc[nt] = __builtin_amdgcn_mfma_f32_32x32x16_bf16(paE[kt].v, vbE, oacc[nt], 0, 0, 0);
        bf16x8 vbO = *(const bf16x8*)(Vt + (vrow * 256 + ((kt * 64 + 32 + hi * 16) ^ vsw)));
        oacc[nt] = __builtin_amdgcn_mfma_f32_32x32x16_bf16(paO[kt].v, vbO, oacc[nt], 0, 0, 0);
      }
    __builtin_amdgcn_s_setprio(0);

    // ---- scatter V(tile+2) into VB[(tile+2)%3] ----
    if (tile + 2 < 16) {
      char* VtN = smem + 32768 + ((tile + 2) % 3) * 16384;
#pragma unroll
      for (int p = 0; p < 2; ++p) {
        const ushort* vs = (const ushort*)&vreg[p];
#pragma unroll
        for (int e = 0; e < 8; ++e) {
          const int d = vsg[p] * 8 + e;
          *(ushort*)(VtN + d * 256 +
                     ((vk[p] * 2) ^ (((e ^ vsg[p]) & 7) << 4))) = vs[e];
        }
      }
    }
  };

  __syncthreads();  // tiles 0,1 staged (drains prologue K loads + scatters)

  f32x16 sacc0[4], sacc1[4];
  qkt(sacc0, 0);

  for (int tt = 0; tt < 8; ++tt) {
    iter(sacc0, sacc1, 2 * tt);
    iter(sacc1, sacc0, 2 * tt + 1);
  }

  const float inv = 1.0f / lsum;
#pragma unroll
  for (int r = 0; r < 16; ++r) {
    const int crow = (r & 3) + 8 * (r >> 2) + 4 * hi;
    const float ir = __shfl(inv, crow);
    const long orow = (long)b * 2048 + qw0 + crow;
#pragma unroll
    for (int nt = 0; nt < 2; ++nt)
      Oout[orow * 1024 + h * 64 + nt * 32 + lq] = __float2bfloat16(oacc[nt][r] * ir);
  }
}

extern "C" void kernel_launch(void* const* d_in, const int* in_sizes, int n_in,
                              void* d_out, int out_size, void* d_ws, size_t ws_size,
                              hipStream_t stream) {
  const float* X = (const float*)d_in[0];
  const int* pmask = (const int*)d_in[1];
  const float* W_Q = (const float*)d_in[2];
  const float* W_K = (const float*)d_in[3];
  const float* W_V = (const float*)d_in[4];
  const float* W_O = (const float*)d_in[5];
  const float* g1 = (const float*)d_in[6];
  const float* b1 = (const float*)d_in[7];
  const float* W1 = (const float*)d_in[8];
  const float* bias1 = (const float*)d_in[9];
  const float* W2 = (const float*)d_in[10];
  const float* bias2 = (const float*)d_in[11];
  const float* g2 = (const float*)d_in[12];
  const float* b2 = (const float*)d_in[13];
  (void)in_sizes; (void)n_in; (void)out_size; (void)ws_size;

  char* ws = (char*)d_ws;
  const size_t MB = 1ull << 20;
  bf16* W1_t   = (bf16*)(ws + 0);
  bf16* Wqkv_t = (bf16*)(ws + 8 * MB);
  bf16* Wo_t   = (bf16*)(ws + 14 * MB);
  bf16* W2_t   = (bf16*)(ws + 16 * MB);
  bf16* xn     = (bf16*)(ws + 24 * MB);
  bf16* QKV    = (bf16*)(ws + 32 * MB);
  bf16* attnb  = (bf16*)(ws + 56 * MB);
  bf16* ff1    = (bf16*)(ws + 32 * MB);
  float* p0o   = (float*)(ws + 64 * MB);
  float* p1o   = (float*)(ws + 32 * MB);
  float* p0    = (float*)(ws + 64 * MB);
  float* p1    = (float*)(ws + 0);
  float* res1  = (float*)d_out;

  transpose_all_ln<<<16384, 256, 0, stream>>>(W_Q, W_K, W_V, W_O, W1, W2,
                                              Wqkv_t, W1_t, W2_t,
                                              X, g1, b1, xn);
  gemm_bt<0, 1><<<32 * 24, 256, 0, stream>>>(xn, Wqkv_t, 4096, 3072, 1024, 1024, 1024,
                                             nullptr, nullptr, nullptr, QKV);
  attn_kernel<<<dim3(32, 8), 512, 0, stream>>>(QKV, pmask, attnb);
  gemm_bt<4, 2><<<2 * 32 * 8, 256, 0, stream>>>(attnb, Wo_t, 4096, 1024, 512, 1024, 1024,
                                                nullptr, nullptr, p1o, p0o);
  oproj_reduce_ln<<<4096, 256, 0, stream>>>(p0o, p1o, X, g2, b2, res1, xn);
  gemm_bt<2, 1><<<32 * 32, 256, 0, stream>>>(xn, W1_t, 4096, 4096, 1024, 1024, 1024,
                                             bias1, nullptr, nullptr, ff1);
  gemm_bt<5, 2><<<2 * 32 * 8, 256, 0, stream>>>(ff1, W2_t, 4096, 1024, 2048, 4096, 4096,
                                                bias2, res1, p1, p0);
  ff2_reduce<<<4096, 256, 0, stream>>>(p0, p1, res1);
}

// Round 16
// 260.683 us; speedup vs baseline: 1.2777x; 1.2777x over previous
//
#include <hip/hip_runtime.h>
#include <hip/hip_bf16.h>

// EncoderLayer on MI355X (gfx950).
// B=2, S=2048, D=1024, H=16, DK=64. M = B*S = 4096.
// R16: REVERT attention to R14 (T15 att[2] spilled to scratch: WRITE_SIZE
//      8MB->43MB, attn 70->146us; lambdas w/ array-reference state violated
//      rule #20). This file == R14 (best: 259.5us).
//      attn: 8w/256q/KVBLK=128, T5 setprio, T13 defer-rescale, permlane swap.
//      GEMM: 128^2, BK=64, A ring-3 depth-2 prefetch, counted vmcnt, swizzled
//      async staging. Fused O-proj-reduce+LN2, FF2 split-K+reduce.

using bf16 = __hip_bfloat16;
typedef __attribute__((ext_vector_type(4))) float f32x4;
typedef __attribute__((ext_vector_type(16))) float f32x16;
typedef __attribute__((ext_vector_type(8))) short bf16x8;

#define DEVI static __device__ __forceinline__

DEVI void async_copy16(const void* g, void* l) {
  __builtin_amdgcn_global_load_lds(
      (const __attribute__((address_space(1))) void*)g,
      (__attribute__((address_space(3))) void*)l, 16, 0, 0);
}

DEVI ushort f2bf_bits(float v) {
  __hip_bfloat16 h = __float2bfloat16(v);
  return *reinterpret_cast<ushort*>(&h);
}

DEVI float bfbits2f(ushort u) {
  union { float f; unsigned int i; } x;
  x.i = ((unsigned int)u) << 16;
  return x.f;
}

DEVI unsigned int pk2(float lo, float hi) {
  return (unsigned int)f2bf_bits(lo) | ((unsigned int)f2bf_bits(hi) << 16);
}

// ---- merged: weight transposes (blocks 0..12287) + LN1 (blocks 12288+) ----
__global__ __launch_bounds__(256) void transpose_all_ln(
    const float* __restrict__ q, const float* __restrict__ k,
    const float* __restrict__ v, const float* __restrict__ o,
    const float* __restrict__ w1, const float* __restrict__ w2,
    bf16* __restrict__ wqkvo, bf16* __restrict__ w1t, bf16* __restrict__ w2t,
    const float* __restrict__ X, const float* __restrict__ g1,
    const float* __restrict__ b1, bf16* __restrict__ xn) {
  const int tid = blockIdx.x;
  if (tid >= 12288) {
    const long row = tid - 12288;
    const int t = threadIdx.x;
    float4 x = ((const float4*)(X + row * 1024))[t];
    float s = x.x + x.y + x.z + x.w;
    float s2 = x.x * x.x + x.y * x.y + x.z * x.z + x.w * x.w;
#pragma unroll
    for (int m = 1; m < 64; m <<= 1) {
      s += __shfl_xor(s, m);
      s2 += __shfl_xor(s2, m);
    }
    __shared__ float red[8];
    const int w = t >> 6, l = t & 63;
    if (l == 0) { red[w] = s; red[4 + w] = s2; }
    __syncthreads();
    s = red[0] + red[1] + red[2] + red[3];
    s2 = red[4] + red[5] + red[6] + red[7];
    const float mean = s * (1.0f / 1024.0f);
    const float var = s2 * (1.0f / 1024.0f) - mean * mean;
    const float rstd = rsqrtf(var + 1e-6f);
    float4 g4 = ((const float4*)g1)[t];
    float4 b4 = ((const float4*)b1)[t];
    union { ushort h[4]; uint2 u; } oo;
    oo.h[0] = f2bf_bits(g4.x * (x.x - mean) * rstd + b4.x);
    oo.h[1] = f2bf_bits(g4.y * (x.y - mean) * rstd + b4.y);
    oo.h[2] = f2bf_bits(g4.z * (x.z - mean) * rstd + b4.z);
    oo.h[3] = f2bf_bits(g4.w * (x.w - mean) * rstd + b4.w);
    ((uint2*)(xn + row * 1024))[t] = oo.u;
    return;
  }
  const float* W;
  bf16* Wt;
  int K, N, n0, k0;
  if (tid < 4096) {
    const int z = tid >> 10, r = tid & 1023;
    W = (z == 0) ? q : (z == 1) ? k : (z == 2) ? v : o;
    Wt = wqkvo + (size_t)z * 1024 * 1024;
    K = 1024; N = 1024; n0 = (r & 31) << 5; k0 = (r >> 5) << 5;
  } else if (tid < 8192) {
    const int r = tid - 4096;
    W = w1; Wt = w1t; K = 1024; N = 4096;
    n0 = (r & 127) << 5; k0 = (r >> 7) << 5;
  } else {
    const int r = tid - 8192;
    W = w2; Wt = w2t; K = 4096; N = 1024;
    n0 = (r & 31) << 5; k0 = (r >> 5) << 5;
  }
  __shared__ float tile[32][33];
  const int tx = threadIdx.x & 31, ty = threadIdx.x >> 5;
#pragma unroll
  for (int i = 0; i < 32; i += 8)
    tile[ty + i][tx] = W[(long)(k0 + ty + i) * N + n0 + tx];
  __syncthreads();
#pragma unroll
  for (int i = 0; i < 32; i += 8)
    Wt[(long)(n0 + ty + i) * K + k0 + tx] = __float2bfloat16(tile[tx][ty + i]);
}

// ---- O-proj split-K reduce fused with LN2: res = p0+p1+X; xn = LN(res) ----
__global__ __launch_bounds__(256) void oproj_reduce_ln(
    const float* __restrict__ p0, const float* __restrict__ p1,
    const float* __restrict__ X, const float* __restrict__ gamma,
    const float* __restrict__ beta, float* __restrict__ res_out,
    bf16* __restrict__ xn_out) {
  const long row = blockIdx.x;
  const int t = threadIdx.x;
  const long i = row * 256 + t;
  const float4 a = ((const float4*)p0)[i];
  const float4 b = ((const float4*)p1)[i];
  const float4 c = ((const float4*)X)[i];
  float4 x;
  x.x = a.x + b.x + c.x; x.y = a.y + b.y + c.y;
  x.z = a.z + b.z + c.z; x.w = a.w + b.w + c.w;
  ((float4*)res_out)[i] = x;
  float s = x.x + x.y + x.z + x.w;
  float s2 = x.x * x.x + x.y * x.y + x.z * x.z + x.w * x.w;
#pragma unroll
  for (int m = 1; m < 64; m <<= 1) {
    s += __shfl_xor(s, m);
    s2 += __shfl_xor(s2, m);
  }
  __shared__ float red[8];
  const int w = t >> 6, l = t & 63;
  if (l == 0) { red[w] = s; red[4 + w] = s2; }
  __syncthreads();
  s = red[0] + red[1] + red[2] + red[3];
  s2 = red[4] + red[5] + red[6] + red[7];
  const float mean = s * (1.0f / 1024.0f);
  const float var = s2 * (1.0f / 1024.0f) - mean * mean;
  const float rstd = rsqrtf(var + 1e-6f);
  float4 g4 = ((const float4*)gamma)[t];
  float4 b4 = ((const float4*)beta)[t];
  union { ushort h[4]; uint2 u; } o;
  o.h[0] = f2bf_bits(g4.x * (x.x - mean) * rstd + b4.x);
  o.h[1] = f2bf_bits(g4.y * (x.y - mean) * rstd + b4.y);
  o.h[2] = f2bf_bits(g4.z * (x.z - mean) * rstd + b4.z);
  o.h[3] = f2bf_bits(g4.w * (x.w - mean) * rstd + b4.w);
  ((uint2*)(xn_out + row * 1024))[t] = o.u;
}

// ---------------- GEMM: C(MxN) = A(MxK,bf16) * Bt(NxK,bf16)^T ----------------
// 128x128 tile, BK=64, 4 waves. A ring-3 (depth-2 prefetch) + B dbuf, counted
// vmcnt(12)/(8)/(0); barrier pair per iter. 80KB LDS (2 blocks/CU).
template <int EPI, int KSPLIT>
__global__ __launch_bounds__(256) void gemm_bt(
    const bf16* __restrict__ A, const bf16* __restrict__ Bt,
    const int M, const int N, const int K, const int lda, const int ldb,
    const float* __restrict__ bias, const float* __restrict__ res,
    float* __restrict__ pother, void* __restrict__ Cout) {
  __shared__ __align__(16) char gsmem[81920];
  const int t = threadIdx.x;
  const int w = t >> 6, l = t & 63;
  const int nb = N >> 7;
  const int cpx = gridDim.x >> 3;
  int bidx = (blockIdx.x & 7) * cpx + (blockIdx.x >> 3);
  int sl = 0;
  if (KSPLIT == 2) {
    const int half = gridDim.x >> 1;
    sl = bidx >= half;
    bidx -= sl * half;
  }
  const int bm = bidx / nb, bn = bidx % nb;
  const long row0 = (long)bm << 7, col0 = (long)bn << 7;
  const int wr = (w >> 1) << 6, wc = (w & 1) << 6;
  const int lr = l & 15;
  const int lkb = (l >> 4) << 4;

  f32x4 acc[4][4];
#pragma unroll
  for (int m = 0; m < 4; ++m)
#pragma unroll
    for (int n = 0; n < 4; ++n) acc[m][n] = (f32x4){0.f, 0.f, 0.f, 0.f};

  const int rA = t >> 3;
  const int g = (t & 7) ^ ((t >> 3) & 7);
  const bf16* gA = A + (row0 + rA) * (long)lda + (long)sl * K + g * 8;
  const bf16* gB = Bt + (col0 + rA) * (long)ldb + (long)sl * K + g * 8;
  char* const Bbase = gsmem + 49152;

  const int nt = K >> 6;
#pragma unroll
  for (int cr = 0; cr < 4; ++cr)
    async_copy16(gA + (long)cr * 32 * lda, gsmem + t * 16 + cr * 4096);
#pragma unroll
  for (int cr = 0; cr < 4; ++cr)
    async_copy16(gB + (long)cr * 32 * ldb, Bbase + t * 16 + cr * 4096);
#pragma unroll
  for (int cr = 0; cr < 4; ++cr)
    async_copy16(gA + (long)cr * 32 * lda + 64, gsmem + 16384 + t * 16 + cr * 4096);
  int curB = 0;

  for (int kt = 0; kt < nt; ++kt) {
    if (kt + 1 < nt) {
      const int k1 = (kt + 1) << 6;
      char* dstB = Bbase + (curB ^ 1) * 16384;
#pragma unroll
      for (int cr = 0; cr < 4; ++cr)
        async_copy16(gB + (long)cr * 32 * ldb + k1, dstB + t * 16 + cr * 4096);
    }
    if (kt + 2 < nt) {
      const int k2 = (kt + 2) << 6;
      char* dstA = gsmem + ((kt + 2) % 3) * 16384;
#pragma unroll
      for (int cr = 0; cr < 4; ++cr)
        async_copy16(gA + (long)cr * 32 * lda + k2, dstA + t * 16 + cr * 4096);
    }
    if (kt < nt - 2) {
      asm volatile("s_waitcnt vmcnt(12)" ::: "memory");
    } else if (kt == nt - 2) {
      asm volatile("s_waitcnt vmcnt(8)" ::: "memory");
    } else {
      asm volatile("s_waitcnt vmcnt(0)" ::: "memory");
    }
    __builtin_amdgcn_s_barrier();
    __builtin_amdgcn_sched_barrier(0);
    const char* As = gsmem + (kt % 3) * 16384;
    const char* Bs = Bbase + curB * 16384;
#pragma unroll
    for (int ks = 0; ks < 2; ++ks) {
      bf16x8 af[4], bfr[4];
#pragma unroll
      for (int m = 0; m < 4; ++m) {
        const int row = wr + m * 16 + lr;
        af[m] = *(const bf16x8*)(As +
            (row * 128 + ((ks * 64 + lkb) ^ ((row & 7) << 4))));
      }
#pragma unroll
      for (int n = 0; n < 4; ++n) {
        const int row = wc + n * 16 + lr;
        bfr[n] = *(const bf16x8*)(Bs +
            (row * 128 + ((ks * 64 + lkb) ^ ((row & 7) << 4))));
      }
#pragma unroll
      for (int m = 0; m < 4; ++m)
#pragma unroll
        for (int n = 0; n < 4; ++n)
          acc[m][n] = __builtin_amdgcn_mfma_f32_16x16x32_bf16(af[m], bfr[n], acc[m][n], 0, 0, 0);
    }
    __builtin_amdgcn_sched_barrier(0);
    __builtin_amdgcn_s_barrier();
    curB ^= 1;
  }

  bf16* Cb = (bf16*)Cout;
  float* Cf = (float*)Cout;
  if ((EPI == 4 || EPI == 5) && sl == 1) Cf = pother;
#pragma unroll
  for (int m = 0; m < 4; ++m) {
#pragma unroll
    for (int r = 0; r < 4; ++r) {
      const long crow = row0 + wr + m * 16 + ((l >> 4) << 2) + r;
      const long rbase = crow * N;
#pragma unroll
      for (int n = 0; n < 4; ++n) {
        const long ccol = col0 + wc + n * 16 + lr;
        float v = acc[m][n][r];
        if (EPI == 2) {
          const float vv = v + bias[ccol];
          const float u2 = vv * (1.5957691216f + 0.0713548162f * vv * vv);
          v = vv / (1.0f + __expf(-u2));
        }
        if (EPI == 5 && sl == 0) v += bias[ccol] + res[rbase + ccol];
        if (EPI == 0 || EPI == 2)
          Cb[rbase + ccol] = __float2bfloat16(v);
        else
          Cf[rbase + ccol] = v;
      }
    }
  }
}

// ---- split-K reduce: out = p0 + p1 (p0 already holds bias+residual) ----
__global__ __launch_bounds__(256) void ff2_reduce(
    const float* __restrict__ p0, const float* __restrict__ p1,
    float* __restrict__ out) {
  const int idx = blockIdx.x * 256 + threadIdx.x;
  const float4 x = ((const float4*)p0)[idx];
  const float4 y = ((const float4*)p1)[idx];
  float4 a;
  a.x = x.x + y.x; a.y = x.y + y.y; a.z = x.z + y.z; a.w = x.w + y.w;
  ((float4*)out)[idx] = a;
}

// ---------------- flash attention: 8 waves, 256 q-rows, KVBLK=128 ------------
// T5 setprio; T13 defer-rescale; permlane32_swap P-exchange. (R14-proven.)
__global__ __launch_bounds__(512) void attn_kernel(
    const bf16* __restrict__ QKV, const int* __restrict__ pmask,
    bf16* __restrict__ Oout) {
  const int bh = blockIdx.x;
  const int b = bh >> 4, h = bh & 15;
  const int q0 = blockIdx.y << 8;
  const int t = threadIdx.x;
  const int w = t >> 6, l = t & 63;
  const int lq = l & 31, hi = l >> 5;

  __shared__ __align__(16) char smem[65536];

  const long base = (long)b * 2048 * 3072;
  const bf16* Qg = QKV + base + h * 64;
  const bf16* Kg = QKV + base + 1024 + h * 64;
  const bf16* Vg = QKV + base + 2048 + h * 64;

  int kSrc[2], kDst[2], vk[2], vsg[2];
#pragma unroll
  for (int p = 0; p < 2; ++p) {
    const int c = p * 512 + t;
    const int kr = c >> 3;
    kSrc[p] = kr * 3072 + (((c & 7) ^ (kr & 7)) << 3);
    kDst[p] = c * 16;
    vk[p] = c >> 3;
    vsg[p] = c & 7;
  }

  const int qw0 = q0 + w * 32;
  bf16x8 qf[4];
#pragma unroll
  for (int dc = 0; dc < 4; ++dc) {
    uint4 raw = *(const uint4*)(Qg + (long)(qw0 + lq) * 3072 + dc * 16 + hi * 8);
    union { uint4 u4; ushort us[8]; } in; in.u4 = raw;
    union { bf16x8 v; ushort us[8]; } o;
#pragma unroll
    for (int e = 0; e < 8; ++e) o.us[e] = f2bf_bits(0.125f * bfbits2f(in.us[e]));
    qf[dc] = o.v;
  }

  union { unsigned int u[4]; bf16x8 v; } bones;
  bones.u[0] = (hi == 0) ? 0x00003F80u : 0u;
  bones.u[1] = bones.u[2] = bones.u[3] = 0u;

  uint4 vreg[2];
#pragma unroll
  for (int p = 0; p < 2; ++p) {
    vreg[p] = *(const uint4*)(Vg + (long)vk[p] * 3072 + vsg[p] * 8);
    async_copy16(Kg + kSrc[p], smem + kDst[p]);
  }
#pragma unroll
  for (int p = 0; p < 2; ++p) {
    const ushort* vs = (const ushort*)&vreg[p];
#pragma unroll
    for (int e = 0; e < 8; ++e) {
      const int d = vsg[p] * 8 + e;
      *(ushort*)(smem + 32768 + d * 256 +
                 ((vk[p] * 2) ^ (((e ^ vsg[p]) & 7) << 4))) = vs[e];
    }
  }

  f32x16 oacc[2];
#pragma unroll
  for (int nt = 0; nt < 2; ++nt)
#pragma unroll
    for (int r = 0; r < 16; ++r) oacc[nt][r] = 0.f;
  float mrun = -3.0e38f, lsum = 0.f;
  int cur = 0;

  __syncthreads();

  for (int ktg = 0; ktg < 16; ++ktg) {
    if (ktg < 15) {
      const long nrow0 = (long)(ktg + 1) * 128 * 3072;
#pragma unroll
      for (int p = 0; p < 2; ++p) {
        vreg[p] = *(const uint4*)(Vg + nrow0 + (long)vk[p] * 3072 + vsg[p] * 8);
        async_copy16(Kg + nrow0 + kSrc[p], smem + (cur ^ 1) * 16384 + kDst[p]);
      }
    }
    const int k0 = ktg << 7;
    const char* Ks = smem + cur * 16384;
    const char* Vt = smem + 32768 + cur * 16384;

    f32x16 sacc[4];
    __builtin_amdgcn_s_setprio(1);
#pragma unroll
    for (int kt = 0; kt < 4; ++kt) {
#pragma unroll
      for (int r = 0; r < 16; ++r) sacc[kt][r] = 0.f;
#pragma unroll
      for (int dc = 0; dc < 4; ++dc) {
        bf16x8 ka = *(const bf16x8*)(Ks +
            ((kt * 32 + lq) * 128 + ((dc * 32 + hi * 16) ^ ((lq & 7) << 4))));
        sacc[kt] = __builtin_amdgcn_mfma_f32_32x32x16_bf16(ka, qf[dc], sacc[kt], 0, 0, 0);
      }
      const int mv = pmask[b * 2048 + k0 + kt * 32 + lq];
      union { unsigned int u[4]; bf16x8 v; } aadd;
      aadd.u[0] = (hi == 0 && mv == 0) ? (unsigned int)f2bf_bits(-1.0e9f) : 0u;
      aadd.u[1] = aadd.u[2] = aadd.u[3] = 0u;
      sacc[kt] = __builtin_amdgcn_mfma_f32_32x32x16_bf16(aadd.v, bones.v, sacc[kt], 0, 0, 0);
    }
    __builtin_amdgcn_s_setprio(0);

    float tmax = -3.0e38f;
#pragma unroll
    for (int kt = 0; kt < 4; ++kt)
#pragma unroll
      for (int r = 0; r < 16; ++r) tmax = fmaxf(tmax, sacc[kt][r]);
    tmax = fmaxf(tmax, __shfl_xor(tmax, 32));
    const bool need = (bool)__any(tmax > mrun + 8.0f);
    const float mnew = need ? fmaxf(mrun, tmax) : mrun;
    float psum = 0.f;
#pragma unroll
    for (int kt = 0; kt < 4; ++kt)
#pragma unroll
      for (int r = 0; r < 16; ++r) {
        const float p = __expf(sacc[kt][r] - mnew);
        sacc[kt][r] = p;
        psum += p;
      }
    psum += __shfl_xor(psum, 32);
    if (need) {
      const float alpha = __expf(mrun - mnew);
      mrun = mnew;
      lsum = lsum * alpha + psum;
#pragma unroll
      for (int r = 0; r < 16; ++r) {
        const float ar = __shfl(alpha, (r & 3) + 8 * (r >> 2) + 4 * hi);
        oacc[0][r] *= ar;
        oacc[1][r] *= ar;
      }
    } else {
      lsum += psum;
    }

    // ---- P -> bf16 A-fragments via pack + permlane32_swap (T12) ----
    union { unsigned int u[4]; bf16x8 v; } paE[4], paO[4];
#pragma unroll
    for (int kt = 0; kt < 4; ++kt) {
      unsigned int c0 = pk2(sacc[kt][0], sacc[kt][1]);
      unsigned int c1 = pk2(sacc[kt][2], sacc[kt][3]);
      unsigned int c2 = pk2(sacc[kt][4], sacc[kt][5]);
      unsigned int c3 = pk2(sacc[kt][6], sacc[kt][7]);
      unsigned int c4 = pk2(sacc[kt][8], sacc[kt][9]);
      unsigned int c5 = pk2(sacc[kt][10], sacc[kt][11]);
      unsigned int c6 = pk2(sacc[kt][12], sacc[kt][13]);
      unsigned int c7 = pk2(sacc[kt][14], sacc[kt][15]);
      asm volatile("v_permlane32_swap_b32 %0, %1" : "+v"(c0), "+v"(c2));
      asm volatile("v_permlane32_swap_b32 %0, %1" : "+v"(c1), "+v"(c3));
      asm volatile("v_permlane32_swap_b32 %0, %1" : "+v"(c4), "+v"(c6));
      asm volatile("v_permlane32_swap_b32 %0, %1" : "+v"(c5), "+v"(c7));
      paE[kt].u[0] = c0; paE[kt].u[1] = c1; paE[kt].u[2] = c2; paE[kt].u[3] = c3;
      paO[kt].u[0] = c4; paO[kt].u[1] = c5; paO[kt].u[2] = c6; paO[kt].u[3] = c7;
    }

    __builtin_amdgcn_s_setprio(1);
#pragma unroll
    for (int kt = 0; kt < 4; ++kt)
#pragma unroll
      for (int nt = 0; nt < 2; ++nt) {
        const int vrow = nt * 32 + lq;
        const int vsw = ((vrow & 7) ^ ((vrow >> 3) & 7)) << 4;
        bf16x8 vbE = *(const bf16x8*)(Vt + (vrow * 256 + ((kt * 64 + hi * 16) ^ vsw)));
        oacc[nt] = __builtin_amdgcn_mfma_f32_32x32x16_bf16(paE[kt].v, vbE, oacc[nt], 0, 0, 0);
        bf16x8 vbO = *(const bf16x8*)(Vt + (vrow * 256 + ((kt * 64 + 32 + hi * 16) ^ vsw)));
        oacc[nt] = __builtin_amdgcn_mfma_f32_32x32x16_bf16(paO[kt].v, vbO, oacc[nt], 0, 0, 0);
      }
    __builtin_amdgcn_s_setprio(0);

    if (ktg < 15) {
      char* VtN = smem + 32768 + (cur ^ 1) * 16384;
#pragma unroll
      for (int p = 0; p < 2; ++p) {
        const ushort* vs = (const ushort*)&vreg[p];
#pragma unroll
        for (int e = 0; e < 8; ++e) {
          const int d = vsg[p] * 8 + e;
          *(ushort*)(VtN + d * 256 +
                     ((vk[p] * 2) ^ (((e ^ vsg[p]) & 7) << 4))) = vs[e];
        }
      }
    }

    __syncthreads();
    cur ^= 1;
  }

  const float inv = 1.0f / lsum;
#pragma unroll
  for (int r = 0; r < 16; ++r) {
    const int crow = (r & 3) + 8 * (r >> 2) + 4 * hi;
    const float ir = __shfl(inv, crow);
    const long orow = (long)b * 2048 + qw0 + crow;
#pragma unroll
    for (int nt = 0; nt < 2; ++nt)
      Oout[orow * 1024 + h * 64 + nt * 32 + lq] = __float2bfloat16(oacc[nt][r] * ir);
  }
}

extern "C" void kernel_launch(void* const* d_in, const int* in_sizes, int n_in,
                              void* d_out, int out_size, void* d_ws, size_t ws_size,
                              hipStream_t stream) {
  const float* X = (const float*)d_in[0];
  const int* pmask = (const int*)d_in[1];
  const float* W_Q = (const float*)d_in[2];
  const float* W_K = (const float*)d_in[3];
  const float* W_V = (const float*)d_in[4];
  const float* W_O = (const float*)d_in[5];
  const float* g1 = (const float*)d_in[6];
  const float* b1 = (const float*)d_in[7];
  const float* W1 = (const float*)d_in[8];
  const float* bias1 = (const float*)d_in[9];
  const float* W2 = (const float*)d_in[10];
  const float* bias2 = (const float*)d_in[11];
  const float* g2 = (const float*)d_in[12];
  const float* b2 = (const float*)d_in[13];
  (void)in_sizes; (void)n_in; (void)out_size; (void)ws_size;

  char* ws = (char*)d_ws;
  const size_t MB = 1ull << 20;
  bf16* W1_t   = (bf16*)(ws + 0);
  bf16* Wqkv_t = (bf16*)(ws + 8 * MB);
  bf16* Wo_t   = (bf16*)(ws + 14 * MB);
  bf16* W2_t   = (bf16*)(ws + 16 * MB);
  bf16* xn     = (bf16*)(ws + 24 * MB);
  bf16* QKV    = (bf16*)(ws + 32 * MB);
  bf16* attnb  = (bf16*)(ws + 56 * MB);
  bf16* ff1    = (bf16*)(ws + 32 * MB);
  float* p0o   = (float*)(ws + 64 * MB);
  float* p1o   = (float*)(ws + 32 * MB);
  float* p0    = (float*)(ws + 64 * MB);
  float* p1    = (float*)(ws + 0);
  float* res1  = (float*)d_out;

  transpose_all_ln<<<16384, 256, 0, stream>>>(W_Q, W_K, W_V, W_O, W1, W2,
                                              Wqkv_t, W1_t, W2_t,
                                              X, g1, b1, xn);
  gemm_bt<0, 1><<<32 * 24, 256, 0, stream>>>(xn, Wqkv_t, 4096, 3072, 1024, 1024, 1024,
                                             nullptr, nullptr, nullptr, QKV);
  attn_kernel<<<dim3(32, 8), 512, 0, stream>>>(QKV, pmask, attnb);
  gemm_bt<4, 2><<<2 * 32 * 8, 256, 0, stream>>>(attnb, Wo_t, 4096, 1024, 512, 1024, 1024,
                                                nullptr, nullptr, p1o, p0o);
  oproj_reduce_ln<<<4096, 256, 0, stream>>>(p0o, p1o, X, g2, b2, res1, xn);
  gemm_bt<2, 1><<<32 * 32, 256, 0, stream>>>(xn, W1_t, 4096, 4096, 1024, 1024, 1024,
                                             bias1, nullptr, nullptr, ff1);
  gemm_bt<5, 2><<<2 * 32 * 8, 256, 0, stream>>>(ff1, W2_t, 4096, 1024, 2048, 4096, 4096,
                                                bias2, res1, p1, p0);
  ff2_reduce<<<4096, 256, 0, stream>>>(p0, p1, res1);
}